// Round 16
// baseline (142.655 us; speedup 1.0000x reference)
//
#include <hip/hip_runtime.h>

typedef __fp16 f16;
typedef __fp16 f16x2 __attribute__((ext_vector_type(2)));
typedef __fp16 f16x8 __attribute__((ext_vector_type(8)));
typedef float f32x4 __attribute__((ext_vector_type(4)));
typedef float f32x16 __attribute__((ext_vector_type(16)));

__device__ __forceinline__ unsigned pkrtz(float a, float b) {
    f16x2 r = __builtin_amdgcn_cvt_pkrtz(a, b);
    return __builtin_bit_cast(unsigned, r);
}

__device__ __forceinline__ f16x8 pack4(unsigned a, unsigned b, unsigned c, unsigned d) {
    union { unsigned u[4]; f16x8 v; } r;
    r.u[0] = a; r.u[1] = b; r.u[2] = c; r.u[3] = d;
    return r.v;
}

// Pack 30 weight matrices (64x64, row=k input, col=m output) into f16
// A-fragment order for v_mfma_f32_32x32x16_f16:
//   lane l holds A[m = l&31][k = 16*kt + 4*(l>>5) + (e&3) + 8*(e>=4)], mtile adds 32 to m.
__global__ __launch_bounds__(512) void pack_w(
    const float* __restrict__ sW1, const float* __restrict__ sW2, const float* __restrict__ sW3,
    const float* __restrict__ tW1, const float* __restrict__ tW2, const float* __restrict__ tW3,
    f16* __restrict__ wp) {
    int mat = blockIdx.x;            // layer*6 + {sW1,sW2,sW3,tW1,tW2,tW3}
    int layer = mat / 6;
    int rem = mat % 6;
    int fi = threadIdx.x >> 6;       // 0..7
    int lane = threadIdx.x & 63;
    int tile = fi >> 2, kt = fi & 3;
    int h = lane >> 5;
    int m = (lane & 31) + 32 * tile;
    const float* Wt[6] = {sW1, sW2, sW3, tW1, tW2, tW3};
    const float* W = Wt[rem] + layer * 4096;
    f16x8 v;
#pragma unroll
    for (int e = 0; e < 8; ++e) {
        int k = 16 * kt + 4 * h + (e & 3) + ((e >> 2) << 3);
        v[e] = (f16)W[k * 64 + m];
    }
    *(f16x8*)(wp + ((size_t)mat * 8 + fi) * 512 + lane * 8) = v;
}

// Pack 30 bias vectors (64 f32) into [layer][{s1,s2,s3,t1,t2,t3}][64] at wb.
__global__ __launch_bounds__(512) void pack_b(
    const float* __restrict__ sb1, const float* __restrict__ sb2, const float* __restrict__ sb3,
    const float* __restrict__ tb1, const float* __restrict__ tb2, const float* __restrict__ tb3,
    float* __restrict__ wb) {
    int i = blockIdx.x * 512 + threadIdx.x;
    if (i >= 1920) return;
    int l = i / 384, r = i % 384, mat = r / 64, j = r % 64;
    const float* B[6] = {sb1, sb2, sb3, tb1, tb2, tb3};
    wb[l * 384 + mat * 64 + j] = B[mat][l * 64 + j];
}

// Dual-rowtile 64x64 GEMM: weight fragment read ONCE from LDS feeds both
// row-tiles' MFMAs (halves LDS traffic per row). 8 ds_read_b128, 16 MFMA,
// 4 independent accumulator chains. Bias (LDS broadcast) read once.
__device__ __forceinline__ void gemm2nt(const f16* w, const f16x8 in[2][4],
                                        const float* bias, int lane, f32x16 c[2][2]) {
    const int h = (lane >> 5) & 1;
#pragma unroll
    for (int mt = 0; mt < 2; ++mt) {
#pragma unroll
        for (int r4 = 0; r4 < 4; ++r4) {
            f32x4 bb = *(const f32x4*)(bias + 32 * mt + 8 * r4 + 4 * h);
#pragma unroll
            for (int j = 0; j < 4; ++j) {
                c[0][mt][4 * r4 + j] = bb[j];
                c[1][mt][4 * r4 + j] = bb[j];
            }
        }
    }
#pragma unroll
    for (int mt = 0; mt < 2; ++mt) {
#pragma unroll
        for (int kt = 0; kt < 4; ++kt) {
            f16x8 wf = *(const f16x8*)(w + (mt * 4 + kt) * 512 + lane * 8);
            c[0][mt] = __builtin_amdgcn_mfma_f32_32x32x16_f16(wf, in[0][kt], c[0][mt], 0, 0, 0);
            c[1][mt] = __builtin_amdgcn_mfma_f32_32x32x16_f16(wf, in[1][kt], c[1][mt], 0, 0, 0);
        }
    }
}

// leaky_relu (packed f16) + pack into next GEMM's B fragments.
// B-frag[kt][e] = C[mt = kt>>1][reg = 8*(kt&1) + e]  (register-local, no cross-lane)
__device__ __forceinline__ void relu_pack(const f32x16 c[2], f16x8 o[4]) {
    const f16 hc = (f16)0.01f;
    const f16x8 c001 = {hc, hc, hc, hc, hc, hc, hc, hc};
#pragma unroll
    for (int kt = 0; kt < 4; ++kt) {
        const int tl = kt >> 1;
        const int base = 8 * (kt & 1);
        f16x8 v = pack4(pkrtz(c[tl][base + 0], c[tl][base + 1]),
                        pkrtz(c[tl][base + 2], c[tl][base + 3]),
                        pkrtz(c[tl][base + 4], c[tl][base + 5]),
                        pkrtz(c[tl][base + 6], c[tl][base + 7]));
        o[kt] = __builtin_elementwise_max(v, v * c001);   // v_pk_max / v_pk_mul
    }
}

// 3-GEMM MLP over 2 row-tiles.
__device__ __forceinline__ void mlp3_2nt(const f16* w, const f16x8 x0f[2][4],
                                         const float* bias, int lane, f32x16 out[2][2]) {
    f32x16 c1[2][2];
    gemm2nt(w, x0f, bias, lane, c1);
    f16x8 h1[2][4];
    relu_pack(c1[0], h1[0]);
    relu_pack(c1[1], h1[1]);
    f32x16 c2[2][2];
    gemm2nt(w + 4096, h1, bias + 64, lane, c2);
    f16x8 h2[2][4];
    relu_pack(c2[0], h2[0]);
    relu_pack(c2[1], h2[1]);
    gemm2nt(w + 8192, h2, bias + 128, lane, out);
}

// Per-buffer: 24576 f16 weights (s@0, t@12288) + 384 f32 biases = 50688 B.
#define BUFSZ 25344

__global__ __launch_bounds__(512)
__attribute__((amdgpu_waves_per_eu(2, 2)))   // pin exactly 2 waves/EU: VGPR budget 256, no squeeze-to-128
void flow_main(const float* __restrict__ x, const f16* __restrict__ wp,
               float* __restrict__ out, int nrows) {
    __shared__ f16 wl[2 * BUFSZ];   // double-buffered layer weights+biases, 101376 B
    const int tid = threadIdx.x;
    const int lane = tid & 63;
    const int wv = tid >> 6;                                    // 0..7
    const int h = lane >> 5;
    const int n0 = (blockIdx.x * 8 + wv) * 64 + (lane & 31);    // 64 rows per wave (2 ntiles)
    const float* wbias_g = (const float*)((const char*)wp + 491520);

    // Prologue: stage layer 0 (weights + biases) into regs.
    f32x4 stg[6];
    f32x4 stgb = {0.f, 0.f, 0.f, 0.f};
    {
        const f32x4* src = (const f32x4*)wp;
#pragma unroll
        for (int i = 0; i < 6; ++i) stg[i] = src[tid + 512 * i];
        if (tid < 96) stgb = ((const f32x4*)wbias_g)[tid];
    }

    // Load x0 (B-fragment gather) + x1 (packed f16, 16 regs/ntile); copy x0 to z.
    f16x8 x0f[2][4];
    f16x8 x1h[2][4];   // x1h[nt][t*2+q] = features {32t+16q+4h+j, 32t+16q+8+4h+j}
#pragma unroll
    for (int nt = 0; nt < 2; ++nt) {
        const float* xr = x + (size_t)(n0 + 32 * nt) * 128;
        float* zr = out + (size_t)(n0 + 32 * nt) * 128;
#pragma unroll
        for (int kt = 0; kt < 4; ++kt) {
            f32x4 a = *(const f32x4*)(xr + 16 * kt + 4 * h);
            f32x4 b = *(const f32x4*)(xr + 16 * kt + 8 + 4 * h);
            *(f32x4*)(zr + 16 * kt + 4 * h) = a;
            *(f32x4*)(zr + 16 * kt + 8 + 4 * h) = b;
            x0f[nt][kt] = pack4(pkrtz(a[0], a[1]), pkrtz(a[2], a[3]),
                                pkrtz(b[0], b[1]), pkrtz(b[2], b[3]));
        }
#pragma unroll
        for (int i = 0; i < 4; ++i) {
            const int t = i >> 1, q = i & 1;
            f32x4 a = *(const f32x4*)(xr + 64 + 32 * t + 16 * q + 4 * h);
            f32x4 b = *(const f32x4*)(xr + 64 + 32 * t + 16 * q + 8 + 4 * h);
            x1h[nt][i] = pack4(pkrtz(a[0], a[1]), pkrtz(a[2], a[3]),
                               pkrtz(b[0], b[1]), pkrtz(b[2], b[3]));
        }
    }

    // Write layer-0 stage to buf0.
    {
        f32x4* dst = (f32x4*)wl;
#pragma unroll
        for (int i = 0; i < 6; ++i) dst[tid + 512 * i] = stg[i];
        if (tid < 96) ((f32x4*)((char*)wl + 49152))[tid] = stgb;
    }
    __syncthreads();

    float ldn[2] = {0.f, 0.f};
#pragma unroll 1
    for (int l = 0; l < 5; ++l) {
        const int cur = l & 1;
        const f16* bufc = wl + cur * BUFSZ;
        const float* bias = (const float*)(bufc + 24576);   // [s1,s2,s3,t1,t2,t3] x 64

        // Prefetch next layer into registers (T14).
        if (l < 4) {
            const f32x4* src = (const f32x4*)(wp + (size_t)(l + 1) * 24576);
#pragma unroll
            for (int i = 0; i < 6; ++i) stg[i] = src[tid + 512 * i];
            if (tid < 96) stgb = ((const f32x4*)(wbias_g + (l + 1) * 384))[tid];
        }

        // ---- s path (both ntiles) ----
        f32x16 cs[2][2];
        mlp3_2nt(bufc, x0f, bias, lane, cs);
        // tanh + logdet + x1 *= exp(s)  (cs dies here)
#pragma unroll
        for (int nt = 0; nt < 2; ++nt) {
#pragma unroll
            for (int i = 0; i < 4; ++i) {
                const int t = i >> 1, q = i & 1;
                f16x8 xo = x1h[nt][i];
                float nf[8];
#pragma unroll
                for (int e = 0; e < 8; ++e) {
                    float y = cs[nt][t][8 * q + e];
                    float u = __builtin_amdgcn_exp2f(2.8853900817779268f * y);  // e^{2y}
                    float rc = __builtin_amdgcn_rcpf(u + 1.f);
                    float s = fmaf(-2.f, rc, 1.f);                              // tanh
                    ldn[nt] += s;
                    float ef = __builtin_amdgcn_exp2f(fmaf(-2.8853900817779268f, rc, 1.4426950408889634f)); // e^{s}
                    nf[e] = (float)xo[e] * ef;
                }
                x1h[nt][i] = pack4(pkrtz(nf[0], nf[1]), pkrtz(nf[2], nf[3]),
                                   pkrtz(nf[4], nf[5]), pkrtz(nf[6], nf[7]));
            }
        }

        // ---- t path ----
        f32x16 c1[2][2];
        gemm2nt(bufc + 12288, x0f, bias + 192, lane, c1);
        f16x8 h1[2][4];
        relu_pack(c1[0], h1[0]);
        relu_pack(c1[1], h1[1]);
        f32x16 c2[2][2];
        gemm2nt(bufc + 16384, h1, bias + 256, lane, c2);
        f16x8 h2[2][4];
        relu_pack(c2[0], h2[0]);
        relu_pack(c2[1], h2[1]);

        // Write prefetched layer l+1 to back buffer (overlaps final GEMM).
        if (l < 4) {
            f32x4* dst = (f32x4*)(wl + (cur ^ 1) * BUFSZ);
#pragma unroll
            for (int i = 0; i < 6; ++i) dst[tid + 512 * i] = stg[i];
            if (tid < 96) ((f32x4*)((char*)(wl + (cur ^ 1) * BUFSZ) + 49152))[tid] = stgb;
        }

        f32x16 ct[2][2];
        gemm2nt(bufc + 20480, h2, bias + 320, lane, ct);

        // x1 += t
#pragma unroll
        for (int nt = 0; nt < 2; ++nt) {
#pragma unroll
            for (int i = 0; i < 4; ++i) {
                const int t = i >> 1, q = i & 1;
                f16x8 xo = x1h[nt][i];
                float nf[8];
#pragma unroll
                for (int e = 0; e < 8; ++e)
                    nf[e] = (float)xo[e] + ct[nt][t][8 * q + e];
                x1h[nt][i] = pack4(pkrtz(nf[0], nf[1]), pkrtz(nf[2], nf[3]),
                                   pkrtz(nf[4], nf[5]), pkrtz(nf[6], nf[7]));
            }
        }

        __syncthreads();   // one barrier/layer
    }

    // Store z[:, 64:] and log_det.
#pragma unroll
    for (int nt = 0; nt < 2; ++nt) {
        float* zr = out + (size_t)(n0 + 32 * nt) * 128;
#pragma unroll
        for (int i = 0; i < 4; ++i) {
            const int t = i >> 1, q = i & 1;
            f16x8 v = x1h[nt][i];
            f32x4 a = {(float)v[0], (float)v[1], (float)v[2], (float)v[3]};
            f32x4 b = {(float)v[4], (float)v[5], (float)v[6], (float)v[7]};
            *(f32x4*)(zr + 64 + 32 * t + 16 * q + 4 * h) = a;
            *(f32x4*)(zr + 64 + 32 * t + 16 * q + 8 + 4 * h) = b;
        }
        float tot = ldn[nt] + __shfl_xor(ldn[nt], 32);
        if (h == 0) out[(size_t)nrows * 128 + n0 + 32 * nt] = tot;
    }
}

extern "C" void kernel_launch(void* const* d_in, const int* in_sizes, int n_in,
                              void* d_out, int out_size, void* d_ws, size_t ws_size,
                              hipStream_t stream) {
    const float* x   = (const float*)d_in[0];
    const float* sW1 = (const float*)d_in[1];
    const float* sb1 = (const float*)d_in[2];
    const float* sW2 = (const float*)d_in[3];
    const float* sb2 = (const float*)d_in[4];
    const float* sW3 = (const float*)d_in[5];
    const float* sb3 = (const float*)d_in[6];
    const float* tW1 = (const float*)d_in[7];
    const float* tb1 = (const float*)d_in[8];
    const float* tW2 = (const float*)d_in[9];
    const float* tb2 = (const float*)d_in[10];
    const float* tW3 = (const float*)d_in[11];
    const float* tb3 = (const float*)d_in[12];

    f16* wp = (f16*)d_ws;      // weights: 240 KB frag-packed; biases: 7.5 KB at +480 KB
    float* wb = (float*)((char*)d_ws + 491520);
    int nrows = in_sizes[0] / 128;

    pack_w<<<30, 512, 0, stream>>>(sW1, sW2, sW3, tW1, tW2, tW3, wp);
    pack_b<<<4, 512, 0, stream>>>(sb1, sb2, sb3, tb1, tb2, tb3, wb);
    flow_main<<<nrows / 512, 512, 0, stream>>>(x, wp, (float*)d_out, nrows);
}

// Round 17
// 139.981 us; speedup vs baseline: 1.0191x; 1.0191x over previous
//
#include <hip/hip_runtime.h>

typedef __fp16 f16;
typedef __fp16 f16x2 __attribute__((ext_vector_type(2)));
typedef __fp16 f16x8 __attribute__((ext_vector_type(8)));
typedef float f32x4 __attribute__((ext_vector_type(4)));
typedef float f32x16 __attribute__((ext_vector_type(16)));

__device__ __forceinline__ unsigned pkrtz(float a, float b) {
    f16x2 r = __builtin_amdgcn_cvt_pkrtz(a, b);
    return __builtin_bit_cast(unsigned, r);
}

__device__ __forceinline__ f16x8 pack4(unsigned a, unsigned b, unsigned c, unsigned d) {
    union { unsigned u[4]; f16x8 v; } r;
    r.u[0] = a; r.u[1] = b; r.u[2] = c; r.u[3] = d;
    return r.v;
}

// Pack 30 weight matrices (64x64, row=k input, col=m output) into f16
// A-fragment order for v_mfma_f32_32x32x16_f16:
//   lane l holds A[m = l&31][k = 16*kt + 4*(l>>5) + (e&3) + 8*(e>=4)], mtile adds 32 to m.
__global__ __launch_bounds__(512) void pack_w(
    const float* __restrict__ sW1, const float* __restrict__ sW2, const float* __restrict__ sW3,
    const float* __restrict__ tW1, const float* __restrict__ tW2, const float* __restrict__ tW3,
    f16* __restrict__ wp) {
    int mat = blockIdx.x;            // layer*6 + {sW1,sW2,sW3,tW1,tW2,tW3}
    int layer = mat / 6;
    int rem = mat % 6;
    int fi = threadIdx.x >> 6;       // 0..7
    int lane = threadIdx.x & 63;
    int tile = fi >> 2, kt = fi & 3;
    int h = lane >> 5;
    int m = (lane & 31) + 32 * tile;
    const float* Wt[6] = {sW1, sW2, sW3, tW1, tW2, tW3};
    const float* W = Wt[rem] + layer * 4096;
    f16x8 v;
#pragma unroll
    for (int e = 0; e < 8; ++e) {
        int k = 16 * kt + 4 * h + (e & 3) + ((e >> 2) << 3);
        v[e] = (f16)W[k * 64 + m];
    }
    *(f16x8*)(wp + ((size_t)mat * 8 + fi) * 512 + lane * 8) = v;
}

// Pack 30 bias vectors (64 f32) into [layer][{s1,s2,s3,t1,t2,t3}][64] at wb.
__global__ __launch_bounds__(512) void pack_b(
    const float* __restrict__ sb1, const float* __restrict__ sb2, const float* __restrict__ sb3,
    const float* __restrict__ tb1, const float* __restrict__ tb2, const float* __restrict__ tb3,
    float* __restrict__ wb) {
    int i = blockIdx.x * 512 + threadIdx.x;
    if (i >= 1920) return;
    int l = i / 384, r = i % 384, mat = r / 64, j = r % 64;
    const float* B[6] = {sb1, sb2, sb3, tb1, tb2, tb3};
    wb[l * 384 + mat * 64 + j] = B[mat][l * 64 + j];
}

// bias pointer is LDS-resident (broadcast ds_read).
__device__ __forceinline__ void bias_init(const float* bias, int h, f32x16 c[2]) {
#pragma unroll
    for (int t = 0; t < 2; ++t) {
#pragma unroll
        for (int r4 = 0; r4 < 4; ++r4) {
            f32x4 bb = *(const f32x4*)(bias + 32 * t + 8 * r4 + 4 * h);
            c[t][4 * r4 + 0] = bb[0];
            c[t][4 * r4 + 1] = bb[1];
            c[t][4 * r4 + 2] = bb[2];
            c[t][4 * r4 + 3] = bb[3];
        }
    }
}

// Paired 64x64 GEMMs (s and t), 16 MFMAs, 4 independent chains. (even waves)
__device__ __forceinline__ void gemm_pair(const f16* wS, const f16* wT,
                                          const f16x8 inS[4], const f16x8 inT[4],
                                          const float* bS, const float* bT,
                                          int lane, f32x16 cs[2], f32x16 ct[2]) {
    const int h = (lane >> 5) & 1;
    bias_init(bS, h, cs);
    bias_init(bT, h, ct);
    __builtin_amdgcn_s_setprio(1);
#pragma unroll
    for (int t = 0; t < 2; ++t) {
#pragma unroll
        for (int kt = 0; kt < 4; ++kt) {
            f16x8 a = *(const f16x8*)(wS + (t * 4 + kt) * 512 + lane * 8);
            f16x8 b = *(const f16x8*)(wT + (t * 4 + kt) * 512 + lane * 8);
            cs[t] = __builtin_amdgcn_mfma_f32_32x32x16_f16(a, inS[kt], cs[t], 0, 0, 0);
            ct[t] = __builtin_amdgcn_mfma_f32_32x32x16_f16(b, inT[kt], ct[t], 0, 0, 0);
        }
    }
    __builtin_amdgcn_s_setprio(0);
}

// Single-path 64x64 GEMM, 8 MFMAs, 2 chains. (odd waves)
__device__ __forceinline__ void gemm1(const f16* w, const f16x8 in[4],
                                      const float* bias, int lane, f32x16 c[2]) {
    const int h = (lane >> 5) & 1;
    bias_init(bias, h, c);
    __builtin_amdgcn_s_setprio(1);
#pragma unroll
    for (int mt = 0; mt < 2; ++mt) {
#pragma unroll
        for (int kt = 0; kt < 4; ++kt) {
            f16x8 wf = *(const f16x8*)(w + (mt * 4 + kt) * 512 + lane * 8);
            c[mt] = __builtin_amdgcn_mfma_f32_32x32x16_f16(wf, in[kt], c[mt], 0, 0, 0);
        }
    }
    __builtin_amdgcn_s_setprio(0);
}

// leaky_relu (packed f16) + pack into next GEMM's B fragments.
// B-frag[kt][e] = C[tile = kt>>1][reg = 8*(kt&1) + e]  (register-local)
__device__ __forceinline__ void relu_pack(const f32x16 c[2], f16x8 o[4]) {
    const f16 hc = (f16)0.01f;
    const f16x8 c001 = {hc, hc, hc, hc, hc, hc, hc, hc};
#pragma unroll
    for (int kt = 0; kt < 4; ++kt) {
        const int tl = kt >> 1;
        const int base = 8 * (kt & 1);
        f16x8 v = pack4(pkrtz(c[tl][base + 0], c[tl][base + 1]),
                        pkrtz(c[tl][base + 2], c[tl][base + 3]),
                        pkrtz(c[tl][base + 4], c[tl][base + 5]),
                        pkrtz(c[tl][base + 6], c[tl][base + 7]));
        o[kt] = __builtin_elementwise_max(v, v * c001);   // v_pk_max / v_pk_mul
    }
}

__device__ __forceinline__ void mlp3_1(const f16* w, const f16x8 x0f[4],
                                       const float* bias, int lane, f32x16 out[2]) {
    f32x16 c1[2];
    gemm1(w, x0f, bias, lane, c1);
    f16x8 h1[4];
    relu_pack(c1, h1);
    f32x16 c2[2];
    gemm1(w + 4096, h1, bias + 64, lane, c2);
    f16x8 h2[4];
    relu_pack(c2, h2);
    gemm1(w + 8192, h2, bias + 128, lane, out);
}

// Per-buffer: 24576 f16 weights (s@0, t@12288) + 384 f32 biases = 50688 B.
#define BUFSZ 25344

__global__ __launch_bounds__(512, 2)
void flow_main(const float* __restrict__ x, const f16* __restrict__ wp,
               float* __restrict__ out, int nrows) {
    __shared__ f16 wl[2 * BUFSZ];   // double-buffered layer weights+biases, 101376 B
    const int tid = threadIdx.x;
    const int lane = tid & 63;
    const int wv = tid >> 6;                                    // 0..7
    const int h = lane >> 5;
    const int n = (blockIdx.x * 8 + wv) * 32 + (lane & 31);     // 32 rows per wave
    const float* xr = x + (size_t)n * 128;
    float* zr = out + (size_t)n * 128;
    const float* wbias_g = (const float*)((const char*)wp + 491520);
    const bool depair = (wv & 4);   // SIMD i hosts wv i (paired) and wv i+4 (de-paired)

    // Prologue: stage layer 0 (weights + biases) into buf0.
    f32x4 stg[6];
    f32x4 stgb = {0.f, 0.f, 0.f, 0.f};
    {
        const f32x4* src = (const f32x4*)wp;
#pragma unroll
        for (int i = 0; i < 6; ++i) stg[i] = src[tid + 512 * i];
        if (tid < 96) stgb = ((const f32x4*)wbias_g)[tid];
    }

    // Load x0 (B-fragment gather), copy to z[:, :64], convert to f16 frags.
    f16x8 x0f[4];
#pragma unroll
    for (int kt = 0; kt < 4; ++kt) {
        f32x4 a = *(const f32x4*)(xr + 16 * kt + 4 * h);
        f32x4 b = *(const f32x4*)(xr + 16 * kt + 8 + 4 * h);
        *(f32x4*)(zr + 16 * kt + 4 * h) = a;
        *(f32x4*)(zr + 16 * kt + 8 + 4 * h) = b;
        x0f[kt] = pack4(pkrtz(a[0], a[1]), pkrtz(a[2], a[3]), pkrtz(b[0], b[1]), pkrtz(b[2], b[3]));
    }

    // x1 resident in registers across all layers.
    f32x4 x1v[8];
#pragma unroll
    for (int t = 0; t < 2; ++t)
#pragma unroll
        for (int r4 = 0; r4 < 4; ++r4)
            x1v[t * 4 + r4] = *(const f32x4*)(xr + 64 + 32 * t + 8 * r4 + 4 * h);

    // Write layer-0 stage to buf0.
    {
        f32x4* dst = (f32x4*)wl;
#pragma unroll
        for (int i = 0; i < 6; ++i) dst[tid + 512 * i] = stg[i];
        if (tid < 96) ((f32x4*)((char*)wl + 49152))[tid] = stgb;
    }
    __syncthreads();

    float ld = 0.f;
#pragma unroll 1
    for (int l = 0; l < 5; ++l) {
        const int cur = l & 1;
        const f16* bufc = wl + cur * BUFSZ;
        const float* bias = (const float*)(bufc + 24576);   // [s1,s2,s3,t1,t2,t3] x 64

        // Prefetch next layer into registers (T14).
        if (l < 4) {
            const f32x4* src = (const f32x4*)(wp + (size_t)(l + 1) * 24576);
#pragma unroll
            for (int i = 0; i < 6; ++i) stg[i] = src[tid + 512 * i];
            if (tid < 96) stgb = ((const f32x4*)(wbias_g + (l + 1) * 384))[tid];
        }

        f32x16 c3s[2], c3t[2];

        if (!depair) {
            // ---- even waves: paired body (4 MFMA chains), epilogue at end ----
            f32x16 cs[2], ct[2];
            gemm_pair(bufc, bufc + 12288, x0f, x0f, bias + 0, bias + 192, lane, cs, ct);
            f16x8 h1s[4], h1t[4];
            relu_pack(cs, h1s);
            relu_pack(ct, h1t);
            f32x16 c2s[2], c2t[2];
            gemm_pair(bufc + 4096, bufc + 16384, h1s, h1t, bias + 64, bias + 256, lane, c2s, c2t);
            f16x8 h2s[4], h2t[4];
            relu_pack(c2s, h2s);
            relu_pack(c2t, h2t);

            // dbuf write between GEMM2 and GEMM3 (overlaps final GEMM)
            if (l < 4) {
                f32x4* dst = (f32x4*)(wl + (cur ^ 1) * BUFSZ);
#pragma unroll
                for (int i = 0; i < 6; ++i) dst[tid + 512 * i] = stg[i];
                if (tid < 96) ((f32x4*)((char*)(wl + (cur ^ 1) * BUFSZ) + 49152))[tid] = stgb;
            }

            gemm_pair(bufc + 8192, bufc + 20480, h2s, h2t, bias + 128, bias + 320, lane, c3s, c3t);
        } else {
            // ---- odd waves: de-paired body — s-MLP, epilogue-sized VALU gap
            // lands while even waves are in GEMMs, then t-MLP (MFMA/LDS) lands
            // while even waves run their epilogue. ----
            mlp3_1(bufc, x0f, bias + 0, lane, c3s);

            // dbuf write between the two MLPs
            if (l < 4) {
                f32x4* dst = (f32x4*)(wl + (cur ^ 1) * BUFSZ);
#pragma unroll
                for (int i = 0; i < 6; ++i) dst[tid + 512 * i] = stg[i];
                if (tid < 96) ((f32x4*)((char*)(wl + (cur ^ 1) * BUFSZ) + 49152))[tid] = stgb;
            }

            // apply x1 *= exp(s) now (frees c3s before t-MLP)
#pragma unroll
            for (int t = 0; t < 2; ++t) {
#pragma unroll
                for (int r = 0; r < 16; ++r) {
                    float u = __builtin_amdgcn_exp2f(2.8853900817779268f * c3s[t][r]);
                    float rc = __builtin_amdgcn_rcpf(u + 1.f);
                    float s = fmaf(-2.f, rc, 1.f);
                    ld += s;
                    float e = __builtin_amdgcn_exp2f(fmaf(-2.8853900817779268f, rc, 1.4426950408889634f));
                    x1v[t * 4 + (r >> 2)][r & 3] *= e;
                }
            }

            mlp3_1(bufc + 12288, x0f, bias + 192, lane, c3t);

            // x1 += t
#pragma unroll
            for (int t = 0; t < 2; ++t)
#pragma unroll
                for (int r = 0; r < 16; ++r)
                    x1v[t * 4 + (r >> 2)][r & 3] += c3t[t][r];
        }

        if (!depair) {
            // even-wave epilogue: tanh + logdet + x1 = x1*exp(s) + t
#pragma unroll
            for (int t = 0; t < 2; ++t) {
#pragma unroll
                for (int r = 0; r < 16; ++r) {
                    float u = __builtin_amdgcn_exp2f(2.8853900817779268f * c3s[t][r]);
                    float rc = __builtin_amdgcn_rcpf(u + 1.f);
                    float s = fmaf(-2.f, rc, 1.f);
                    ld += s;
                    float e = __builtin_amdgcn_exp2f(fmaf(-2.8853900817779268f, rc, 1.4426950408889634f));
                    x1v[t * 4 + (r >> 2)][r & 3] =
                        fmaf(x1v[t * 4 + (r >> 2)][r & 3], e, c3t[t][r]);
                }
            }
        }

        __syncthreads();   // one barrier/layer
    }

    // Store z[:, 64:]
#pragma unroll
    for (int t = 0; t < 2; ++t)
#pragma unroll
        for (int r4 = 0; r4 < 4; ++r4)
            *(f32x4*)(zr + 64 + 32 * t + 8 * r4 + 4 * h) = x1v[t * 4 + r4];

    // log_det: lane n holds half the features, lane n+32 the other half.
    float tot = ld + __shfl_xor(ld, 32);
    if (h == 0) out[(size_t)nrows * 128 + n] = tot;
}

extern "C" void kernel_launch(void* const* d_in, const int* in_sizes, int n_in,
                              void* d_out, int out_size, void* d_ws, size_t ws_size,
                              hipStream_t stream) {
    const float* x   = (const float*)d_in[0];
    const float* sW1 = (const float*)d_in[1];
    const float* sb1 = (const float*)d_in[2];
    const float* sW2 = (const float*)d_in[3];
    const float* sb2 = (const float*)d_in[4];
    const float* sW3 = (const float*)d_in[5];
    const float* sb3 = (const float*)d_in[6];
    const float* tW1 = (const float*)d_in[7];
    const float* tb1 = (const float*)d_in[8];
    const float* tW2 = (const float*)d_in[9];
    const float* tb2 = (const float*)d_in[10];
    const float* tW3 = (const float*)d_in[11];
    const float* tb3 = (const float*)d_in[12];

    f16* wp = (f16*)d_ws;      // weights: 240 KB frag-packed; biases: 7.5 KB at +480 KB
    float* wb = (float*)((char*)d_ws + 491520);
    int nrows = in_sizes[0] / 128;

    pack_w<<<30, 512, 0, stream>>>(sW1, sW2, sW3, tW1, tW2, tW3, wp);
    pack_b<<<4, 512, 0, stream>>>(sb1, sb2, sb3, tb1, tb2, tb3, wb);
    flow_main<<<nrows / 256, 512, 0, stream>>>(x, wp, (float*)d_out, nrows);
}

// Round 18
// 117.196 us; speedup vs baseline: 1.2172x; 1.1944x over previous
//
#include <hip/hip_runtime.h>

typedef __fp16 f16;
typedef __fp16 f16x2 __attribute__((ext_vector_type(2)));
typedef __fp16 f16x8 __attribute__((ext_vector_type(8)));
typedef float f32x4 __attribute__((ext_vector_type(4)));
typedef float f32x16 __attribute__((ext_vector_type(16)));

__device__ __forceinline__ unsigned pkrtz(float a, float b) {
    f16x2 r = __builtin_amdgcn_cvt_pkrtz(a, b);
    return __builtin_bit_cast(unsigned, r);
}

__device__ __forceinline__ f16x8 pack4(unsigned a, unsigned b, unsigned c, unsigned d) {
    union { unsigned u[4]; f16x8 v; } r;
    r.u[0] = a; r.u[1] = b; r.u[2] = c; r.u[3] = d;
    return r.v;
}

// Async global->LDS DMA, 16B per lane. LDS dest = uniform base + lane*16.
__device__ __forceinline__ void glds16(const void* g, void* l) {
    __builtin_amdgcn_global_load_lds(
        (const __attribute__((address_space(1))) unsigned*)g,
        (__attribute__((address_space(3))) unsigned*)l, 16, 0, 0);
}

// Pack 30 weight matrices (64x64, row=k input, col=m output) into f16
// A-fragment order for v_mfma_f32_32x32x16_f16:
//   lane l holds A[m = l&31][k = 16*kt + 4*(l>>5) + (e&3) + 8*(e>=4)], mtile adds 32 to m.
__global__ __launch_bounds__(512) void pack_w(
    const float* __restrict__ sW1, const float* __restrict__ sW2, const float* __restrict__ sW3,
    const float* __restrict__ tW1, const float* __restrict__ tW2, const float* __restrict__ tW3,
    f16* __restrict__ wp) {
    int mat = blockIdx.x;            // layer*6 + {sW1,sW2,sW3,tW1,tW2,tW3}
    int layer = mat / 6;
    int rem = mat % 6;
    int fi = threadIdx.x >> 6;       // 0..7
    int lane = threadIdx.x & 63;
    int tile = fi >> 2, kt = fi & 3;
    int h = lane >> 5;
    int m = (lane & 31) + 32 * tile;
    const float* Wt[6] = {sW1, sW2, sW3, tW1, tW2, tW3};
    const float* W = Wt[rem] + layer * 4096;
    f16x8 v;
#pragma unroll
    for (int e = 0; e < 8; ++e) {
        int k = 16 * kt + 4 * h + (e & 3) + ((e >> 2) << 3);
        v[e] = (f16)W[k * 64 + m];
    }
    *(f16x8*)(wp + ((size_t)mat * 8 + fi) * 512 + lane * 8) = v;
}

// Pack 30 bias vectors (64 f32) into [layer][{s1,s2,s3,t1,t2,t3}][64] at wb.
__global__ __launch_bounds__(512) void pack_b(
    const float* __restrict__ sb1, const float* __restrict__ sb2, const float* __restrict__ sb3,
    const float* __restrict__ tb1, const float* __restrict__ tb2, const float* __restrict__ tb3,
    float* __restrict__ wb) {
    int i = blockIdx.x * 512 + threadIdx.x;
    if (i >= 1920) return;
    int l = i / 384, r = i % 384, mat = r / 64, j = r % 64;
    const float* B[6] = {sb1, sb2, sb3, tb1, tb2, tb3};
    wb[l * 384 + mat * 64 + j] = B[mat][l * 64 + j];
}

// bias pointer is LDS-resident (broadcast ds_read).
__device__ __forceinline__ void bias_init(const float* bias, int h, f32x16 c[2]) {
#pragma unroll
    for (int t = 0; t < 2; ++t) {
#pragma unroll
        for (int r4 = 0; r4 < 4; ++r4) {
            f32x4 bb = *(const f32x4*)(bias + 32 * t + 8 * r4 + 4 * h);
            c[t][4 * r4 + 0] = bb[0];
            c[t][4 * r4 + 1] = bb[1];
            c[t][4 * r4 + 2] = bb[2];
            c[t][4 * r4 + 3] = bb[3];
        }
    }
}

// Single-path 64x64 GEMM over a wave's 32 rows, weights+bias from LDS.
__device__ __forceinline__ void gemm1(const f16* w, const f16x8 in[4],
                                      const float* bias, int lane, f32x16 c[2]) {
    const int h = (lane >> 5) & 1;
    bias_init(bias, h, c);
    __builtin_amdgcn_s_setprio(1);
#pragma unroll
    for (int mt = 0; mt < 2; ++mt) {
#pragma unroll
        for (int kt = 0; kt < 4; ++kt) {
            f16x8 wf = *(const f16x8*)(w + (mt * 4 + kt) * 512 + lane * 8);
            c[mt] = __builtin_amdgcn_mfma_f32_32x32x16_f16(wf, in[kt], c[mt], 0, 0, 0);
        }
    }
    __builtin_amdgcn_s_setprio(0);
}

// leaky_relu (packed f16) + pack into next GEMM's B fragments.
// B-frag[kt][e] = C[mt = kt>>1][reg = 8*(kt&1) + e]  (register-local)
__device__ __forceinline__ void relu_pack(const f32x16 c[2], f16x8 o[4]) {
    const f16 hc = (f16)0.01f;
    const f16x8 c001 = {hc, hc, hc, hc, hc, hc, hc, hc};
#pragma unroll
    for (int kt = 0; kt < 4; ++kt) {
        const int tl = kt >> 1;
        const int base = 8 * (kt & 1);
        f16x8 v = pack4(pkrtz(c[tl][base + 0], c[tl][base + 1]),
                        pkrtz(c[tl][base + 2], c[tl][base + 3]),
                        pkrtz(c[tl][base + 4], c[tl][base + 5]),
                        pkrtz(c[tl][base + 6], c[tl][base + 7]));
        o[kt] = __builtin_elementwise_max(v, v * c001);   // v_pk_max / v_pk_mul
    }
}

// 3-GEMM MLP (one path), weights/biases from one LDS slot.
__device__ __forceinline__ void mlp3(const f16* w, const f16x8 x0f[4],
                                     int lane, f32x16 out[2]) {
    const float* bias = (const float*)(w + 12288);
    f32x16 c1[2];
    gemm1(w, x0f, bias, lane, c1);
    f16x8 h1[4];
    relu_pack(c1, h1);
    f32x16 c2[2];
    gemm1(w + 4096, h1, bias + 64, lane, c2);
    f16x8 h2[4];
    relu_pack(c2, h2);
    gemm1(w + 8192, h2, bias + 128, lane, out);
}

// Path slot: 12288 f16 weights + 192 f32 bias = 25344 B.
#define SLOTB 25344

__global__ __launch_bounds__(512, 2)
void flow_main(const float* __restrict__ x, const f16* __restrict__ wp,
               float* __restrict__ out, int nrows) {
    __shared__ char wl[2 * SLOTB];   // slot0 = s-path, slot1 = t-path (alternating DMA)
    const int tid = threadIdx.x;
    const int lane = tid & 63;
    const int wv = tid >> 6;                                    // 0..7
    const int h = lane >> 5;
    const int n = (blockIdx.x * 8 + wv) * 32 + (lane & 31);     // 32 rows per wave
    const float* xr = x + (size_t)n * 128;
    float* zr = out + (size_t)n * 128;
    const char* wp_b = (const char*)wp;            // path pi: weights at pi*24576
    const char* wb_b = (const char*)wp + 491520;   // path pi: bias at pi*768

    // Issue DMA: path pi -> slot (weights 24576B as 24 chunks x 1024B; bias 768B).
    // Wave w covers chunks {w, w+8, w+16}; wave 0 lanes<48 cover bias.
    auto stage = [&](int pi, char* slot) {
#pragma unroll
        for (int j = 0; j < 3; ++j) {
            const int chunk = wv + j * 8;
            glds16(wp_b + (size_t)pi * 24576 + chunk * 1024 + lane * 16,
                   slot + chunk * 1024);
        }
        if (wv == 0 && lane < 48)
            glds16(wb_b + (size_t)pi * 768 + lane * 16, slot + 24576);
    };

    // Prologue: DMA s0 -> slot0.
    stage(0, wl);

    // Load x0 (B-fragment gather), copy to z[:, :64], convert to f16 frags.
    f16x8 x0f[4];
#pragma unroll
    for (int kt = 0; kt < 4; ++kt) {
        f32x4 a = *(const f32x4*)(xr + 16 * kt + 4 * h);
        f32x4 b = *(const f32x4*)(xr + 16 * kt + 8 + 4 * h);
        *(f32x4*)(zr + 16 * kt + 4 * h) = a;
        *(f32x4*)(zr + 16 * kt + 8 + 4 * h) = b;
        x0f[kt] = pack4(pkrtz(a[0], a[1]), pkrtz(a[2], a[3]), pkrtz(b[0], b[1]), pkrtz(b[2], b[3]));
    }

    // x1 resident as packed f16 (16 regs). x1h[t*2+q][e] <-> feature 32t+16q+8*(e>=4)+4h+(e&3)
    f16x8 x1h[4];
#pragma unroll
    for (int i = 0; i < 4; ++i) {
        const int t = i >> 1, q = i & 1;
        f32x4 a = *(const f32x4*)(xr + 64 + 32 * t + 16 * q + 4 * h);
        f32x4 b = *(const f32x4*)(xr + 64 + 32 * t + 16 * q + 8 + 4 * h);
        x1h[i] = pack4(pkrtz(a[0], a[1]), pkrtz(a[2], a[3]),
                       pkrtz(b[0], b[1]), pkrtz(b[2], b[3]));
    }

    __syncthreads();   // implicit vmcnt(0) drain: s0 DMA complete

    float ld = 0.f;
#pragma unroll 1
    for (int l = 0; l < 5; ++l) {
        // ---- s phase: compute from slot0; DMA t_l -> slot1 flies under it ----
        stage(2 * l + 1, wl + SLOTB);

        f32x16 cs[2];
        mlp3((const f16*)wl, x0f, lane, cs);

        // tanh + logdet + x1 *= exp(s)
#pragma unroll
        for (int i = 0; i < 4; ++i) {
            const int t = i >> 1, q = i & 1;
            f16x8 xo = x1h[i];
            float nf[8];
#pragma unroll
            for (int e = 0; e < 8; ++e) {
                float y = cs[t][8 * q + e];
                float u = __builtin_amdgcn_exp2f(2.8853900817779268f * y);  // e^{2y}
                float rc = __builtin_amdgcn_rcpf(u + 1.f);
                float s = fmaf(-2.f, rc, 1.f);                              // tanh
                ld += s;
                float ef = __builtin_amdgcn_exp2f(fmaf(-2.8853900817779268f, rc, 1.4426950408889634f)); // e^{s}
                nf[e] = (float)xo[e] * ef;
            }
            x1h[i] = pack4(pkrtz(nf[0], nf[1]), pkrtz(nf[2], nf[3]),
                           pkrtz(nf[4], nf[5]), pkrtz(nf[6], nf[7]));
        }

        __syncthreads();   // slot0 reads done; slot1 DMA drained (implicit vmcnt 0)

        // ---- t phase: compute from slot1; DMA s_{l+1} -> slot0 flies under it ----
        if (l < 4) stage(2 * l + 2, wl);

        f32x16 ct[2];
        mlp3((const f16*)(wl + SLOTB), x0f, lane, ct);

        // x1 += t
#pragma unroll
        for (int i = 0; i < 4; ++i) {
            const int t = i >> 1, q = i & 1;
            f16x8 xo = x1h[i];
            float nf[8];
#pragma unroll
            for (int e = 0; e < 8; ++e)
                nf[e] = (float)xo[e] + ct[t][8 * q + e];
            x1h[i] = pack4(pkrtz(nf[0], nf[1]), pkrtz(nf[2], nf[3]),
                           pkrtz(nf[4], nf[5]), pkrtz(nf[6], nf[7]));
        }

        __syncthreads();   // slot1 reads done; slot0 DMA drained
    }

    // Store z[:, 64:]
#pragma unroll
    for (int i = 0; i < 4; ++i) {
        const int t = i >> 1, q = i & 1;
        f16x8 v = x1h[i];
        f32x4 a = {(float)v[0], (float)v[1], (float)v[2], (float)v[3]};
        f32x4 b = {(float)v[4], (float)v[5], (float)v[6], (float)v[7]};
        *(f32x4*)(zr + 64 + 32 * t + 16 * q + 4 * h) = a;
        *(f32x4*)(zr + 64 + 32 * t + 16 * q + 8 + 4 * h) = b;
    }

    // log_det: lane n holds half the features, lane n+32 the other half.
    float tot = ld + __shfl_xor(ld, 32);
    if (h == 0) out[(size_t)nrows * 128 + n] = tot;
}

extern "C" void kernel_launch(void* const* d_in, const int* in_sizes, int n_in,
                              void* d_out, int out_size, void* d_ws, size_t ws_size,
                              hipStream_t stream) {
    const float* x   = (const float*)d_in[0];
    const float* sW1 = (const float*)d_in[1];
    const float* sb1 = (const float*)d_in[2];
    const float* sW2 = (const float*)d_in[3];
    const float* sb2 = (const float*)d_in[4];
    const float* sW3 = (const float*)d_in[5];
    const float* sb3 = (const float*)d_in[6];
    const float* tW1 = (const float*)d_in[7];
    const float* tb1 = (const float*)d_in[8];
    const float* tW2 = (const float*)d_in[9];
    const float* tb2 = (const float*)d_in[10];
    const float* tW3 = (const float*)d_in[11];
    const float* tb3 = (const float*)d_in[12];

    f16* wp = (f16*)d_ws;      // weights: 240 KB frag-packed (path-major); biases at +480 KB
    float* wb = (float*)((char*)d_ws + 491520);
    int nrows = in_sizes[0] / 128;

    pack_w<<<30, 512, 0, stream>>>(sW1, sW2, sW3, tW1, tW2, tW3, wp);
    pack_b<<<4, 512, 0, stream>>>(sb1, sb2, sb3, tb1, tb2, tb3, wb);
    flow_main<<<nrows / 256, 512, 0, stream>>>(x, wp, (float*)d_out, nrows);
}